// Round 3
// baseline (146.729 us; speedup 1.0000x reference)
//
#include <hip/hip_runtime.h>
#include <hip/hip_bf16.h>
#include <stdint.h>

#define B_SZ 1024
#define M_SZ 209
#define D_SZ 12288
#define S_SZ 2

#define BT   64              // B rows per block
#define MS   2               // M splits per block-col
#define MTH  112             // c rows per block (7 * 16)
#define NCT  7               // 16-wide col tiles per block
#define KC   48              // split-K chunks
#define KCH  (D_SZ / KC)     // 256
#define BK   64              // K per staging iteration
#define NIT  (KCH / BK)      // 4
#define LDX  72              // LDS row stride in bf16 elems (64 + 8 pad)

// ws layout (floats): [xx: B][cc: M][pad -> 1280][dot: KC*B*M (slab) or B*M (atomic)]
#define WS_DOT_OFF 1280

typedef __attribute__((ext_vector_type(8))) short short8;
typedef __attribute__((ext_vector_type(4))) float floatx4;

__device__ __forceinline__ uint32_t pk2(float lo, float hi) {
    union { __hip_bfloat162 h; uint32_t u; } cv;
    cv.h = __float22bfloat162_rn(float2{lo, hi});
    return cv.u;
}

__device__ __forceinline__ float sq16(const float4& a, const float4& b,
                                      const float4& c, const float4& d) {
    return a.x*a.x + a.y*a.y + a.z*a.z + a.w*a.w
         + b.x*b.x + b.y*b.y + b.z*b.z + b.w*b.w
         + c.x*c.x + c.y*c.y + c.z*c.z + c.w*c.w
         + d.x*d.x + d.y*d.y + d.z*d.z + d.w*d.w;
}

// Fused distance-GEMM: dot(x_i,c_j) split-K partials + ||x||^2 + ||c||^2
// grid = (KC, B/BT, MS) = 1536 blocks -> 6 blocks/CU, 24 waves/CU
__global__ __launch_bounds__(256, 6) void rbf_main(
    const float* __restrict__ x, const float* __restrict__ c,
    float* __restrict__ dot, float* __restrict__ xx, float* __restrict__ cc,
    int atomic_mode)
{
    __shared__ unsigned short sx[BT * LDX];    //  9.2 KB
    __shared__ unsigned short sc[MTH * LDX];   // 16.1 KB

    const int t      = threadIdx.x;
    const int kchunk = blockIdx.x;
    const int bchunk = blockIdx.y;
    const int mchunk = blockIdx.z;
    const int wave   = t >> 6;
    const int lane   = t & 63;
    const int quad   = lane >> 4;
    const int mrow   = lane & 15;

    floatx4 acc[NCT];
    const floatx4 zero4 = {0.f, 0.f, 0.f, 0.f};
#pragma unroll
    for (int i = 0; i < NCT; ++i) acc[i] = zero4;

    const int r     = t >> 2;        // staging row within 64-row band
    const int cbase = (t & 3) * 16;  // 16 contiguous floats per thread

    const float* xp  = x + (size_t)(bchunk * BT + r) * D_SZ + kchunk * KCH + cbase;
    const float* cp0 = c + (size_t)mchunk * MTH * D_SZ + kchunk * KCH + cbase;
    const bool do_cc = (bchunk == 0);

    float sxx = 0.f;
    float scc[2] = {0.f, 0.f};

    for (int it = 0; it < NIT; ++it) {
        // ---- x tile (64x64): 16 floats/thread, cvt_pk -> 2x ds_write_b128
        {
            float4 v0 = *(const float4*)(xp + 0);
            float4 v1 = *(const float4*)(xp + 4);
            float4 v2 = *(const float4*)(xp + 8);
            float4 v3 = *(const float4*)(xp + 12);
            sxx += sq16(v0, v1, v2, v3);
            uint4 w0 = { pk2(v0.x,v0.y), pk2(v0.z,v0.w), pk2(v1.x,v1.y), pk2(v1.z,v1.w) };
            uint4 w1 = { pk2(v2.x,v2.y), pk2(v2.z,v2.w), pk2(v3.x,v3.y), pk2(v3.z,v3.w) };
            *(uint4*)(&sx[r * LDX + cbase])     = w0;
            *(uint4*)(&sx[r * LDX + cbase + 8]) = w1;
        }
        // ---- c tile (112x64): rows 0..63 (all threads), rows 64..111 (r<48)
#pragma unroll
        for (int rb = 0; rb < 2; ++rb) {
            const int crow = rb * 64 + r;
            if (rb == 0 || r < 48) {
                const int  grow  = mchunk * MTH + crow;
                const bool valid = grow < M_SZ;
                const float* p = cp0 + (size_t)crow * D_SZ;
                float4 v0, v1, v2, v3;
                if (valid) {
                    v0 = *(const float4*)(p + 0);  v1 = *(const float4*)(p + 4);
                    v2 = *(const float4*)(p + 8);  v3 = *(const float4*)(p + 12);
                } else {
                    v0 = v1 = v2 = v3 = make_float4(0.f, 0.f, 0.f, 0.f);
                }
                if (do_cc && valid) scc[rb] += sq16(v0, v1, v2, v3);
                uint4 w0 = { pk2(v0.x,v0.y), pk2(v0.z,v0.w), pk2(v1.x,v1.y), pk2(v1.z,v1.w) };
                uint4 w1 = { pk2(v2.x,v2.y), pk2(v2.z,v2.w), pk2(v3.x,v3.y), pk2(v3.z,v3.w) };
                *(uint4*)(&sc[crow * LDX + cbase])     = w0;
                *(uint4*)(&sc[crow * LDX + cbase + 8]) = w1;
            }
        }
        __syncthreads();

        // ---- MFMA: 2 k-steps of 32 over this BK=64 slab
        const unsigned short* ax = &sx[(wave * 16 + mrow) * LDX + quad * 8];
        const unsigned short* bx = &sc[mrow * LDX + quad * 8];
#pragma unroll
        for (int k0 = 0; k0 < BK; k0 += 32) {
            short8 a = *(const short8*)(ax + k0);
#pragma unroll
            for (int ct = 0; ct < NCT; ++ct) {
                short8 b = *(const short8*)(bx + ct * 16 * LDX + k0);
                acc[ct] = __builtin_amdgcn_mfma_f32_16x16x32_bf16(a, b, acc[ct], 0, 0, 0);
            }
        }
        __syncthreads();
        xp += BK;
        cp0 += BK;
    }

    // ---- dot partials (C/D layout: col=lane&15, row=quad*4+reg)
    float* dst = atomic_mode ? dot : dot + (size_t)kchunk * B_SZ * M_SZ;
    const int gi0 = bchunk * BT + wave * 16 + quad * 4;
#pragma unroll
    for (int ct = 0; ct < NCT; ++ct) {
        const int gj = mchunk * MTH + ct * 16 + mrow;
        if (gj < M_SZ) {
#pragma unroll
            for (int rg = 0; rg < 4; ++rg) {
                const size_t idx = (size_t)(gi0 + rg) * M_SZ + gj;
                if (atomic_mode) atomicAdd(&dst[idx], acc[ct][rg]);
                else             dst[idx] = acc[ct][rg];
            }
        }
    }

    // ---- ||x||^2: reduce 4 staging lanes per row -> 1 atomic (mchunk 0 only)
    if (mchunk == 0) {
        sxx += __shfl_down(sxx, 2);
        sxx += __shfl_down(sxx, 1);
        if ((t & 3) == 0) atomicAdd(&xx[bchunk * BT + r], sxx);
    }

    // ---- ||c||^2 (bchunk==0 blocks only; each mchunk covers disjoint rows)
    if (do_cc) {
#pragma unroll
        for (int rb = 0; rb < 2; ++rb) {
            float s = scc[rb];
            s += __shfl_down(s, 2);
            s += __shfl_down(s, 1);
            const int grow = mchunk * MTH + rb * 64 + r;
            if ((t & 3) == 0 && (rb == 0 || r < 48) && grow < M_SZ)
                atomicAdd(&cc[grow], s);
        }
    }
}

// finalize: reduce split-K, d2 = xx + cc - 2*dot, radial = exp(-sqrt/sig^2), @ W^T + b
template <int NKC>
__global__ __launch_bounds__(256) void rbf_fin(
    const float* __restrict__ dot, const float* __restrict__ xx,
    const float* __restrict__ cc, const float* __restrict__ sigma,
    const float* __restrict__ W, const float* __restrict__ bias,
    float* __restrict__ out)
{
    const int wave = threadIdx.x >> 6, lane = threadIdx.x & 63;
    const int i = blockIdx.x * 4 + wave;      // one wave per output row
    const float xxi = xx[i];
    float a0 = 0.f, a1 = 0.f;
    for (int j = lane; j < M_SZ; j += 64) {
        float s = 0.f;
#pragma unroll
        for (int k = 0; k < NKC; ++k)
            s += dot[(size_t)k * B_SZ * M_SZ + (size_t)i * M_SZ + j];
        float d2 = fmaxf(xxi + cc[j] - 2.f * s, 0.f);
        float sg = sigma[j];
        float rad = __expf(-sqrtf(d2) / (sg * sg));
        a0 += rad * W[j];
        a1 += rad * W[M_SZ + j];
    }
#pragma unroll
    for (int off = 32; off > 0; off >>= 1) {
        a0 += __shfl_down(a0, off);
        a1 += __shfl_down(a1, off);
    }
    if (lane == 0) {
        out[i * 2 + 0] = a0 + bias[0];
        out[i * 2 + 1] = a1 + bias[1];
    }
}

extern "C" void kernel_launch(void* const* d_in, const int* in_sizes, int n_in,
                              void* d_out, int out_size, void* d_ws, size_t ws_size,
                              hipStream_t stream)
{
    const float* x     = (const float*)d_in[0];
    const float* c     = (const float*)d_in[1];
    const float* sigma = (const float*)d_in[2];
    const float* W     = (const float*)d_in[3];
    const float* bias  = (const float*)d_in[4];
    float* out = (float*)d_out;

    float* xx  = (float*)d_ws;                 // [B]
    float* cc  = xx + B_SZ;                    // [M]
    float* dot = (float*)d_ws + WS_DOT_OFF;    // slab: [KC,B,M]; atomic: [B,M]

    const size_t slab_bytes = ((size_t)WS_DOT_OFF + (size_t)KC * B_SZ * M_SZ) * 4;
    const int atomic_mode = (ws_size < slab_bytes) ? 1 : 0;

    // zero atomic accumulation targets (xx, cc always; dot too in atomic mode)
    const size_t zero_bytes = atomic_mode
        ? ((size_t)WS_DOT_OFF + (size_t)B_SZ * M_SZ) * 4
        : (size_t)WS_DOT_OFF * 4;
    hipMemsetAsync(d_ws, 0, zero_bytes, stream);

    rbf_main<<<dim3(KC, B_SZ / BT, MS), 256, 0, stream>>>(x, c, dot, xx, cc, atomic_mode);
    if (atomic_mode)
        rbf_fin<1><<<B_SZ / 4, 256, 0, stream>>>(dot, xx, cc, sigma, W, bias, out);
    else
        rbf_fin<KC><<<B_SZ / 4, 256, 0, stream>>>(dot, xx, cc, sigma, W, bias, out);
}

// Round 4
// 119.096 us; speedup vs baseline: 1.2320x; 1.2320x over previous
//
#include <hip/hip_runtime.h>
#include <hip/hip_bf16.h>
#include <stdint.h>

#define B_SZ 1024
#define M_SZ 209
#define MPAD 224            // padded M rows (14 * 16)
#define D_SZ 12288
#define KC   48             // split-K chunks; grid (48,16) -> 768 blocks, XCD = k%8
#define KCH  (D_SZ / KC)    // 256
#define BK   64             // K per staging iteration
#define NIT  (KCH / BK)     // 4
#define NB   16             // B splits
#define BT   64             // B rows per block
#define NCT  14             // 16-wide col tiles

// ws byte offsets (ws >= ~27 MB; harness provides ~268 MB)
#define CBF_OFF  0u                                   // c bf16 [224][12288]
#define XXP_OFF  (MPAD * D_SZ * 2)                    // xx partials [B][KC] f32
#define CC_OFF   (XXP_OFF + B_SZ * KC * 4)            // cc [224] f32
#define SLAB_OFF (CC_OFF + 1024)                      // dot slab [KC][B][M] bf16

typedef __attribute__((ext_vector_type(8))) short short8;
typedef __attribute__((ext_vector_type(4))) float floatx4;

__device__ __forceinline__ uint32_t pk2(float lo, float hi) {
    union { __hip_bfloat162 h; uint32_t u; } cv;
    cv.h = __float22bfloat162_rn(float2{lo, hi});
    return cv.u;
}

__device__ __forceinline__ void gload_lds16(const void* g, void* l) {
    __builtin_amdgcn_global_load_lds(
        (const __attribute__((address_space(1))) void*)g,
        (__attribute__((address_space(3))) void*)l, 16, 0, 0);
}

// ---------------------------------------------------------------------------
// prepass: c fp32 -> bf16 (padded to 224 rows, zeros in pad) + ||c||^2
__global__ __launch_bounds__(256) void rbf_prep(
    const float* __restrict__ c, unsigned short* __restrict__ cbf,
    float* __restrict__ cc)
{
    __shared__ float red[4];
    const int j = blockIdx.x, t = threadIdx.x;
    unsigned short* dst = cbf + (size_t)j * D_SZ;
    float s = 0.f;
    if (j < M_SZ) {
        const float* src = c + (size_t)j * D_SZ;
        for (int i = t * 4; i < D_SZ; i += 1024) {
            float4 v = *(const float4*)(src + i);
            s += v.x*v.x + v.y*v.y + v.z*v.z + v.w*v.w;
            uint2 w = { pk2(v.x, v.y), pk2(v.z, v.w) };
            *(uint2*)(dst + i) = w;
        }
    } else {
        uint2 zz = {0u, 0u};
        for (int i = t * 4; i < D_SZ; i += 1024) *(uint2*)(dst + i) = zz;
    }
#pragma unroll
    for (int off = 32; off > 0; off >>= 1) s += __shfl_down(s, off);
    if ((t & 63) == 0) red[t >> 6] = s;
    __syncthreads();
    if (t == 0 && j < M_SZ) cc[j] = red[0] + red[1] + red[2] + red[3];
}

// ---------------------------------------------------------------------------
// main: split-K distance GEMM. c staged via global_load_lds DMA (bf16,
// XOR-swizzled LDS: chunk' = chunk ^ (row&7), unpadded 128B rows).
// x staged via VGPR (fp32 -> bf16 cvt) into the same swizzled layout.
__global__ __launch_bounds__(256, 3) void rbf_main(
    const float* __restrict__ x, const unsigned short* __restrict__ cbf,
    __hip_bfloat16* __restrict__ slab, float* __restrict__ xxp)
{
    __shared__ unsigned short sx[BT * BK];    //  8 KB
    __shared__ unsigned short sc[MPAD * BK];  // 28 KB

    const int t    = threadIdx.x;
    const int k    = blockIdx.x;   // k-chunk
    const int b    = blockIdx.y;   // b-chunk
    const int wave = t >> 6, lane = t & 63;
    const int quad = lane >> 4, mrow = lane & 15;
    const int m3   = mrow & 7;

    floatx4 acc[NCT];
    const floatx4 z4 = {0.f, 0.f, 0.f, 0.f};
#pragma unroll
    for (int i = 0; i < NCT; ++i) acc[i] = z4;

    // x staging mapping: thread -> (row r, 16 cols), swizzled LDS dest
    const int r  = t >> 2;
    const int c0 = (t & 3) * 2;    // source chunk pair (8 bf16 per chunk)
    const float* xp = x + (size_t)(b * BT + r) * D_SZ + (size_t)k * KCH + (t & 3) * 16;
    unsigned short* xw0 = &sx[r * BK + ((c0    ) ^ (r & 7)) * 8];
    unsigned short* xw1 = &sx[r * BK + ((c0 + 1) ^ (r & 7)) * 8];

    // c DMA: lane L of round cr covers row cr*8 + L/8, LDS chunk L%8.
    // Source chunk = (L%8) ^ (row&7) = (L%8) ^ (L/8 & 7)  (cr*8 = 0 mod 8)
    const int lr8 = lane >> 3, lc8 = lane & 7;
    const unsigned short* cpb = cbf + (size_t)lr8 * D_SZ + (size_t)k * KCH
                              + (size_t)((lc8 ^ lr8) * 8);

    // MFMA fragment read pointers (swizzle folded in; row&7 == mrow&7)
    const unsigned short* ax0 = &sx[(wave * 16 + mrow) * BK + ((quad    ) ^ m3) * 8];
    const unsigned short* ax1 = &sx[(wave * 16 + mrow) * BK + ((quad + 4) ^ m3) * 8];
    const unsigned short* bx0 = &sc[mrow * BK + ((quad    ) ^ m3) * 8];
    const unsigned short* bx1 = &sc[mrow * BK + ((quad + 4) ^ m3) * 8];

    float sxx = 0.f;

    for (int it = 0; it < NIT; ++it) {
        // ---- c tile: 28 DMA rounds of 8 rows (7 per wave), 1 KB each
#pragma unroll
        for (int j = 0; j < 7; ++j) {
            const int cr = wave * 7 + j;
            gload_lds16(cpb + (size_t)cr * 8 * D_SZ + it * BK, &sc[cr * 512]);
        }
        // ---- x tile: 16 fp32/thread -> bf16 -> 2x ds_write_b128 (swizzled)
        {
            float4 v0 = *(const float4*)(xp + 0);
            float4 v1 = *(const float4*)(xp + 4);
            float4 v2 = *(const float4*)(xp + 8);
            float4 v3 = *(const float4*)(xp + 12);
            sxx += v0.x*v0.x + v0.y*v0.y + v0.z*v0.z + v0.w*v0.w
                 + v1.x*v1.x + v1.y*v1.y + v1.z*v1.z + v1.w*v1.w
                 + v2.x*v2.x + v2.y*v2.y + v2.z*v2.z + v2.w*v2.w
                 + v3.x*v3.x + v3.y*v3.y + v3.z*v3.z + v3.w*v3.w;
            uint4 w0 = { pk2(v0.x,v0.y), pk2(v0.z,v0.w), pk2(v1.x,v1.y), pk2(v1.z,v1.w) };
            uint4 w1 = { pk2(v2.x,v2.y), pk2(v2.z,v2.w), pk2(v3.x,v3.y), pk2(v3.z,v3.w) };
            *(uint4*)xw0 = w0;
            *(uint4*)xw1 = w1;
        }
        __syncthreads();

        // ---- MFMA: 2 k-steps of 32 over this BK=64 slab
#pragma unroll
        for (int ks = 0; ks < 2; ++ks) {
            short8 a = *(const short8*)(ks ? ax1 : ax0);
            const unsigned short* bb = ks ? bx1 : bx0;
#pragma unroll
            for (int ct = 0; ct < NCT; ++ct) {
                short8 bf = *(const short8*)(bb + ct * 1024);
                acc[ct] = __builtin_amdgcn_mfma_f32_16x16x32_bf16(a, bf, acc[ct], 0, 0, 0);
            }
        }
        __syncthreads();
        xp += BK;
    }

    // ---- slab write (bf16). C/D layout: col=lane&15, row=quad*4+reg
    __hip_bfloat16* sd = slab + (size_t)k * B_SZ * M_SZ;
    const int gi0 = b * BT + wave * 16 + quad * 4;
#pragma unroll
    for (int ct = 0; ct < NCT; ++ct) {
        const int gj = ct * 16 + mrow;
        if (gj < M_SZ) {
#pragma unroll
            for (int rg = 0; rg < 4; ++rg)
                sd[(size_t)(gi0 + rg) * M_SZ + gj] = __float2bfloat16(acc[ct][rg]);
        }
    }

    // ---- xx partials: 4 staging lanes per row -> xxp[i][k] (no atomics)
    sxx += __shfl_down(sxx, 2);
    sxx += __shfl_down(sxx, 1);
    if ((t & 3) == 0) xxp[(size_t)(b * BT + r) * KC + k] = sxx;
}

// ---------------------------------------------------------------------------
// finalize: reduce split-K slab + xxp, d2 = xx+cc-2dot, radial, @ W^T + b
__global__ __launch_bounds__(256) void rbf_fin(
    const __hip_bfloat16* __restrict__ slab, const float* __restrict__ xxp,
    const float* __restrict__ cc, const float* __restrict__ sigma,
    const float* __restrict__ W, const float* __restrict__ bias,
    float* __restrict__ out)
{
    const int wave = threadIdx.x >> 6, lane = threadIdx.x & 63;
    const int i = blockIdx.x * 4 + wave;      // one wave per output row

    float xv = (lane < KC) ? xxp[(size_t)i * KC + lane] : 0.f;
#pragma unroll
    for (int off = 32; off > 0; off >>= 1) xv += __shfl_down(xv, off);
    const float xxi = __shfl(xv, 0);

    float a0 = 0.f, a1 = 0.f;
    for (int j = lane; j < M_SZ; j += 64) {
        float s = 0.f;
#pragma unroll
        for (int kk = 0; kk < KC; ++kk)
            s += __bfloat162float(slab[(size_t)kk * B_SZ * M_SZ + (size_t)i * M_SZ + j]);
        float d2 = fmaxf(xxi + cc[j] - 2.f * s, 0.f);
        float sg = sigma[j];
        float rad = __expf(-sqrtf(d2) / (sg * sg));
        a0 += rad * W[j];
        a1 += rad * W[M_SZ + j];
    }
#pragma unroll
    for (int off = 32; off > 0; off >>= 1) {
        a0 += __shfl_down(a0, off);
        a1 += __shfl_down(a1, off);
    }
    if (lane == 0) {
        out[i * 2 + 0] = a0 + bias[0];
        out[i * 2 + 1] = a1 + bias[1];
    }
}

// ---------------------------------------------------------------------------
extern "C" void kernel_launch(void* const* d_in, const int* in_sizes, int n_in,
                              void* d_out, int out_size, void* d_ws, size_t ws_size,
                              hipStream_t stream)
{
    const float* x     = (const float*)d_in[0];
    const float* c     = (const float*)d_in[1];
    const float* sigma = (const float*)d_in[2];
    const float* W     = (const float*)d_in[3];
    const float* bias  = (const float*)d_in[4];
    float* out = (float*)d_out;

    char* ws = (char*)d_ws;
    unsigned short*  cbf  = (unsigned short*)(ws + CBF_OFF);
    float*           xxp  = (float*)(ws + XXP_OFF);
    float*           cc   = (float*)(ws + CC_OFF);
    __hip_bfloat16*  slab = (__hip_bfloat16*)(ws + SLAB_OFF);

    rbf_prep<<<MPAD, 256, 0, stream>>>(c, cbf, cc);
    rbf_main<<<dim3(KC, NB), 256, 0, stream>>>(x, cbf, slab, xxp);
    rbf_fin<<<B_SZ / 4, 256, 0, stream>>>(slab, xxp, cc, sigma, W, bias, out);
}

// Round 5
// 113.571 us; speedup vs baseline: 1.2920x; 1.0486x over previous
//
#include <hip/hip_runtime.h>
#include <hip/hip_bf16.h>
#include <stdint.h>

#define B_SZ 1024
#define M_SZ 209
#define MPAD 224            // padded M rows (14 * 16)
#define D_SZ 12288
#define KC   48             // split-K chunks; grid (48,16) -> 768 blocks = 3/CU
#define KCH  (D_SZ / KC)    // 256
#define BK   64             // K per staging iteration
#define NIT  (KCH / BK)     // 4
#define NB   16             // B splits
#define BT   64             // B rows per block
#define NCT  14             // 16-wide col tiles
#define SROW 256            // slab k-stride (elems): 512 B = 4 cache lines
#define SLROW (KC * SROW)   // slab row stride = 12288 elems

// ws byte offsets
#define CBF_OFF  0u                                   // c bf16 [224][12288]
#define XXP_OFF  (MPAD * D_SZ * 2)                    // xx partials [B][KC] f32
#define CC_OFF   (XXP_OFF + B_SZ * KC * 4)            // cc [209] f32
#define SLAB_OFF (CC_OFF + 1024)                      // slab [B][KC][256] bf16

typedef __attribute__((ext_vector_type(8))) short short8;
typedef __attribute__((ext_vector_type(4))) float floatx4;

__device__ __forceinline__ uint32_t pk2(float lo, float hi) {
    union { __hip_bfloat162 h; uint32_t u; } cv;
    cv.h = __float22bfloat162_rn(float2{lo, hi});
    return cv.u;
}

__device__ __forceinline__ float bfbits2f(unsigned short u) {
    union { uint32_t u; float f; } cv;
    cv.u = ((uint32_t)u) << 16;
    return cv.f;
}

__device__ __forceinline__ void gload_lds16(const void* g, void* l) {
    __builtin_amdgcn_global_load_lds(
        (const __attribute__((address_space(1))) void*)g,
        (__attribute__((address_space(3))) void*)l, 16, 0, 0);
}

// ---------------------------------------------------------------------------
// prepass: c fp32 -> bf16 (padded to 224 rows, zeros) + ||c||^2
__global__ __launch_bounds__(256) void rbf_prep(
    const float* __restrict__ c, unsigned short* __restrict__ cbf,
    float* __restrict__ cc)
{
    __shared__ float red[4];
    const int j = blockIdx.x, t = threadIdx.x;
    unsigned short* dst = cbf + (size_t)j * D_SZ;
    float s = 0.f;
    if (j < M_SZ) {
        const float* src = c + (size_t)j * D_SZ;
        for (int i = t * 8; i < D_SZ; i += 2048) {
            float4 v0 = *(const float4*)(src + i);
            float4 v1 = *(const float4*)(src + i + 4);
            s += v0.x*v0.x + v0.y*v0.y + v0.z*v0.z + v0.w*v0.w
               + v1.x*v1.x + v1.y*v1.y + v1.z*v1.z + v1.w*v1.w;
            uint4 w = { pk2(v0.x,v0.y), pk2(v0.z,v0.w), pk2(v1.x,v1.y), pk2(v1.z,v1.w) };
            *(uint4*)(dst + i) = w;
        }
    } else {
        uint4 zz = {0u, 0u, 0u, 0u};
        for (int i = t * 8; i < D_SZ; i += 2048) *(uint4*)(dst + i) = zz;
    }
#pragma unroll
    for (int off = 32; off > 0; off >>= 1) s += __shfl_down(s, off);
    if ((t & 63) == 0) red[t >> 6] = s;
    __syncthreads();
    if (t == 0 && j < M_SZ) cc[j] = red[0] + red[1] + red[2] + red[3];
}

// ---------------------------------------------------------------------------
// main: split-K distance GEMM. c via global_load_lds DMA (XOR-swizzled LDS).
// All NIT x-slabs prefetched+converted in the prologue (no global loads in loop).
__global__ __launch_bounds__(256, 3) void rbf_main(
    const float* __restrict__ x, const unsigned short* __restrict__ cbf,
    __hip_bfloat16* __restrict__ slab, float* __restrict__ xxp)
{
    __shared__ unsigned short sx[BT * BK];    //  8 KB
    __shared__ unsigned short sc[MPAD * BK];  // 28 KB

    const int t    = threadIdx.x;
    const int k    = blockIdx.x;
    const int b    = blockIdx.y;
    const int wave = t >> 6, lane = t & 63;
    const int quad = lane >> 4, mrow = lane & 15;
    const int m3   = mrow & 7;

    floatx4 acc[NCT];
    const floatx4 z4 = {0.f, 0.f, 0.f, 0.f};
#pragma unroll
    for (int i = 0; i < NCT; ++i) acc[i] = z4;

    // ---- prologue: prefetch + convert ALL x for this block's k-slice
    const int r  = t >> 2;
    const int c0 = (t & 3) * 2;
    const float* xp = x + (size_t)(b * BT + r) * D_SZ + (size_t)k * KCH + (t & 3) * 16;

    uint4 xw[NIT][2];
    float sxx = 0.f;
#pragma unroll
    for (int it = 0; it < NIT; ++it) {
        float4 v0 = *(const float4*)(xp + it * BK + 0);
        float4 v1 = *(const float4*)(xp + it * BK + 4);
        float4 v2 = *(const float4*)(xp + it * BK + 8);
        float4 v3 = *(const float4*)(xp + it * BK + 12);
        sxx += v0.x*v0.x + v0.y*v0.y + v0.z*v0.z + v0.w*v0.w
             + v1.x*v1.x + v1.y*v1.y + v1.z*v1.z + v1.w*v1.w
             + v2.x*v2.x + v2.y*v2.y + v2.z*v2.z + v2.w*v2.w
             + v3.x*v3.x + v3.y*v3.y + v3.z*v3.z + v3.w*v3.w;
        xw[it][0] = make_uint4(pk2(v0.x,v0.y), pk2(v0.z,v0.w), pk2(v1.x,v1.y), pk2(v1.z,v1.w));
        xw[it][1] = make_uint4(pk2(v2.x,v2.y), pk2(v2.z,v2.w), pk2(v3.x,v3.y), pk2(v3.z,v3.w));
    }

    unsigned short* xw0 = &sx[r * BK + ((c0    ) ^ (r & 7)) * 8];
    unsigned short* xw1 = &sx[r * BK + ((c0 + 1) ^ (r & 7)) * 8];

    // c DMA: lane L of round cr -> row cr*8 + L/8, LDS chunk L%8,
    // source chunk (L%8) ^ (row&7)
    const int lr8 = lane >> 3, lc8 = lane & 7;
    const unsigned short* cpb = cbf + (size_t)lr8 * D_SZ + (size_t)k * KCH
                              + (size_t)((lc8 ^ lr8) * 8);

    // MFMA fragment pointers (swizzle folded; row&7 == mrow&7 for all rows)
    const unsigned short* ax0 = &sx[(wave * 16 + mrow) * BK + ((quad    ) ^ m3) * 8];
    const unsigned short* ax1 = &sx[(wave * 16 + mrow) * BK + ((quad + 4) ^ m3) * 8];
    const unsigned short* bx0 = &sc[mrow * BK + ((quad    ) ^ m3) * 8];
    const unsigned short* bx1 = &sc[mrow * BK + ((quad + 4) ^ m3) * 8];

    for (int it = 0; it < NIT; ++it) {
        // c tile: 28 DMA rounds of 8 rows (7 per wave), 1 KB each
#pragma unroll
        for (int j = 0; j < 7; ++j) {
            const int cr = wave * 7 + j;
            gload_lds16(cpb + (size_t)cr * 8 * D_SZ + it * BK, &sc[cr * 512]);
        }
        // x tile: stores from prefetched registers
        *(uint4*)xw0 = xw[it][0];
        *(uint4*)xw1 = xw[it][1];
        __syncthreads();

#pragma unroll
        for (int ks = 0; ks < 2; ++ks) {
            short8 a = *(const short8*)(ks ? ax1 : ax0);
            const unsigned short* bb = ks ? bx1 : bx0;
#pragma unroll
            for (int ct = 0; ct < NCT; ++ct) {
                short8 bf = *(const short8*)(bb + ct * 1024);
                acc[ct] = __builtin_amdgcn_mfma_f32_16x16x32_bf16(a, bf, acc[ct], 0, 0, 0);
            }
        }
        __syncthreads();
    }

    // ---- slab write: [i][k][256] bf16 (pad cols j>=209 get dot=0 — c rows zeroed)
    __hip_bfloat16* sd = slab + (size_t)k * SROW;
    const int gi0 = b * BT + wave * 16 + quad * 4;
#pragma unroll
    for (int ct = 0; ct < NCT; ++ct) {
        const int gj = ct * 16 + mrow;
#pragma unroll
        for (int rg = 0; rg < 4; ++rg)
            sd[(size_t)(gi0 + rg) * SLROW + gj] = __float2bfloat16(acc[ct][rg]);
    }

    // ---- xx partials (no atomics)
    sxx += __shfl_down(sxx, 2);
    sxx += __shfl_down(sxx, 1);
    if ((t & 3) == 0) xxp[(size_t)(b * BT + r) * KC + k] = sxx;
}

// ---------------------------------------------------------------------------
// finalize: one block per row. Coalesced short8 slab reads, two-stage LDS
// reduction over k, then radial + W-dot epilogue on wave 0.
__global__ __launch_bounds__(256) void rbf_fin(
    const __hip_bfloat16* __restrict__ slab, const float* __restrict__ xxp,
    const float* __restrict__ cc, const float* __restrict__ sigma,
    const float* __restrict__ W, const float* __restrict__ bias,
    float* __restrict__ out)
{
    __shared__ float jpart[MPAD * 9];   // [j][g]
    __shared__ float jtot[MPAD];
    __shared__ float xsh;

    const int t = threadIdx.x;
    const int i = blockIdx.x;

    // xx reduce (wave 0)
    if (t < 64) {
        float xv = (t < KC) ? xxp[(size_t)i * KC + t] : 0.f;
#pragma unroll
        for (int off = 32; off > 0; off >>= 1) xv += __shfl_down(xv, off);
        if (t == 0) xsh = xv;
    }

    // slab partial sums: thread (o,g): j-octet o (j = o*8..o*8+7), kk = g, g+9, ...
    const int o = t % 28, g = t / 28;
    if (t < 252) {
        const unsigned short* sp = (const unsigned short*)slab
                                 + (size_t)i * SLROW + o * 8;
        float s8[8] = {0.f,0.f,0.f,0.f,0.f,0.f,0.f,0.f};
        for (int kk = g; kk < KC; kk += 9) {
            short8 v = *(const short8*)(sp + kk * SROW);
#pragma unroll
            for (int e = 0; e < 8; ++e) s8[e] += bfbits2f((unsigned short)v[e]);
        }
#pragma unroll
        for (int e = 0; e < 8; ++e) jpart[(o * 8 + e) * 9 + g] = s8[e];
    }
    __syncthreads();

    if (t < MPAD) {
        float d = 0.f;
#pragma unroll
        for (int g2 = 0; g2 < 9; ++g2) d += jpart[t * 9 + g2];
        jtot[t] = d;
    }
    __syncthreads();

    if (t < 64) {
        const float xxi = xsh;
        float a0 = 0.f, a1 = 0.f;
        for (int j = t; j < M_SZ; j += 64) {
            float d2 = fmaxf(xxi + cc[j] - 2.f * jtot[j], 0.f);
            float sg = sigma[j];
            float rad = __expf(-sqrtf(d2) / (sg * sg));
            a0 += rad * W[j];
            a1 += rad * W[M_SZ + j];
        }
#pragma unroll
        for (int off = 32; off > 0; off >>= 1) {
            a0 += __shfl_down(a0, off);
            a1 += __shfl_down(a1, off);
        }
        if (t == 0) {
            out[i * 2 + 0] = a0 + bias[0];
            out[i * 2 + 1] = a1 + bias[1];
        }
    }
}

// ---------------------------------------------------------------------------
extern "C" void kernel_launch(void* const* d_in, const int* in_sizes, int n_in,
                              void* d_out, int out_size, void* d_ws, size_t ws_size,
                              hipStream_t stream)
{
    const float* x     = (const float*)d_in[0];
    const float* c     = (const float*)d_in[1];
    const float* sigma = (const float*)d_in[2];
    const float* W     = (const float*)d_in[3];
    const float* bias  = (const float*)d_in[4];
    float* out = (float*)d_out;

    char* ws = (char*)d_ws;
    unsigned short*  cbf  = (unsigned short*)(ws + CBF_OFF);
    float*           xxp  = (float*)(ws + XXP_OFF);
    float*           cc   = (float*)(ws + CC_OFF);
    __hip_bfloat16*  slab = (__hip_bfloat16*)(ws + SLAB_OFF);

    rbf_prep<<<MPAD, 256, 0, stream>>>(c, cbf, cc);
    rbf_main<<<dim3(KC, NB), 256, 0, stream>>>(x, cbf, slab, xxp);
    rbf_fin<<<B_SZ, 256, 0, stream>>>(slab, xxp, cc, sigma, W, bias, out);
}